// Round 2
// baseline (15.133 us; speedup 1.0000x reference)
//
#include <hip/hip_runtime.h>

#define BATCH 4096
#define NUM_CLASSES 10000
#define FEAT_DIM 512

// One kernel: 256 blocks x 1024 threads (16 waves). One wave per sample,
// 16 samples per block. Each lane handles 8 contiguous floats (2 x float4).
// Per-block partial (pre-scaled by 1/BATCH) -> one atomicAdd to out[0].
// out[0] is zeroed by a hipMemsetAsync node before this kernel each call.
__global__ __launch_bounds__(1024) void center_loss_fused(
    const float* __restrict__ x,
    const int* __restrict__ labels,
    const float* __restrict__ centers,
    float* __restrict__ out)
{
    const int wave = threadIdx.x >> 6;            // 0..15
    const int lane = threadIdx.x & 63;            // 0..63
    const int sample = blockIdx.x * 16 + wave;    // grid=256 -> sample < 4096

    const int label = labels[sample];             // wave-uniform broadcast load

    const float4* __restrict__ xr = (const float4*)(x + (size_t)sample * FEAT_DIM);
    const float4* __restrict__ cr = (const float4*)(centers + (size_t)label * FEAT_DIM);

    // 512 floats = 128 float4s; 64 lanes x 2 float4 each, fully coalesced.
    float4 a0 = xr[lane * 2 + 0];
    float4 a1 = xr[lane * 2 + 1];
    float4 b0 = cr[lane * 2 + 0];
    float4 b1 = cr[lane * 2 + 1];

    float acc = 0.0f;
    float d;
    d = a0.x - b0.x; acc += d * d;
    d = a0.y - b0.y; acc += d * d;
    d = a0.z - b0.z; acc += d * d;
    d = a0.w - b0.w; acc += d * d;
    d = a1.x - b1.x; acc += d * d;
    d = a1.y - b1.y; acc += d * d;
    d = a1.z - b1.z; acc += d * d;
    d = a1.w - b1.w; acc += d * d;

    // wave64 butterfly reduce
    #pragma unroll
    for (int off = 32; off > 0; off >>= 1)
        acc += __shfl_down(acc, off, 64);

    __shared__ float s[16];
    if (lane == 0) s[wave] = acc;
    __syncthreads();

    // wave 0 reduces the 16 per-wave partials and issues ONE atomic per block.
    if (wave == 0) {
        float t = (lane < 16) ? s[lane] : 0.0f;
        #pragma unroll
        for (int off = 8; off > 0; off >>= 1)
            t += __shfl_down(t, off, 64);
        if (lane == 0)
            atomicAdd(out, t * (1.0f / (float)BATCH));
    }
}

extern "C" void kernel_launch(void* const* d_in, const int* in_sizes, int n_in,
                              void* d_out, int out_size, void* d_ws, size_t ws_size,
                              hipStream_t stream) {
    const float* x       = (const float*)d_in[0];
    const int*   labels  = (const int*)d_in[1];
    const float* centers = (const float*)d_in[2];
    float* out = (float*)d_out;

    // Zero the accumulator every call (harness poisons once, never re-poisons).
    hipMemsetAsync(out, 0, sizeof(float), stream);
    center_loss_fused<<<BATCH / 16, 1024, 0, stream>>>(x, labels, centers, out);
}